// Round 20
// baseline (445.062 us; speedup 1.0000x reference)
//
#include <hip/hip_runtime.h>

#define LTOT 13824          // 24*24*24
#define NCH 108             // scan chunks (fine)
#define CHL 128             // chunk length (108*128 = 13824)
#define EPSF 1e-5f

// ---------- workspace layout (floats) ----------
static const size_t OFF_U   = 1024;                 // conv out; DEAD after inproj
static const size_t NU      = (size_t)3*LTOT*64;    // 2654208
static const size_t NXI     = (size_t)3*LTOT*128;   // 5308416
static const size_t NBM     = (size_t)3*LTOT*16;    // 663552
static const size_t NAG     = (size_t)3*NCH*128*16; // 663552
static const size_t OFF_XIT = OFF_U   + NU;         // xiT[(r*128+i)][l]
static const size_t OFF_SZT = OFF_XIT + NXI;        // szT -> becomes yT in-place
static const size_t OFF_DTT = OFF_SZT + NXI;        // dtT[(r*128+i)][l]
static const size_t OFF_BMT = OFF_DTT + NXI;        // BmT[(r*16+n)][l]
static const size_t OFF_CMT = OFF_BMT + NBM;
static const size_t OFF_W2  = OFF_CMT + NBM;        // 384*64
static const size_t OFF_WT  = OFF_W2 + 24576;       // 3*192*64 transposed conv weights
static const size_t OFF_WI  = OFF_WT + 36864;       // in_proj weights transposed [q][col] 64*256
// scan scratch overlaid on dead U region
static const size_t OFF_AGA = OFF_U;
static const size_t OFF_AGB = OFF_U + NAG;
static const size_t OFF_SEED= OFF_U + 2*NAG;
static const size_t OFF_FIN = OFF_DTT;              // dtT dead after scan3

__device__ __forceinline__ float sigm(float x){ return 1.f/(1.f+__expf(-x)); }
__device__ __forceinline__ float siluf(float x){ return x*sigm(x); }
__device__ __forceinline__ float softplusf(float x){
    return fmaxf(x,0.f) + log1pf(__expf(-fabsf(x)));
}

// all-VALU cross-lane adds via DPP (no LDS pipe)
template<int CTRL>
__device__ __forceinline__ float dpp_add(float x){
    int v = __builtin_amdgcn_update_dpp(0, __float_as_int(x), CTRL, 0xf, 0xf, true);
    return x + __int_as_float(v);
}
__device__ __forceinline__ float sum16(float x){   // sum within each 16-lane row
    x = dpp_add<0xB1>(x);    // quad_perm xor1
    x = dpp_add<0x4E>(x);    // quad_perm xor2
    x = dpp_add<0x141>(x);   // row_half_mirror
    x = dpp_add<0x140>(x);   // row_mirror
    return x;
}

// ===== K0: weight prep — conv transpose, out_proj∘conv fusion, in_proj^T ===
__global__ __launch_bounds__(256) void k_prep(const float* __restrict__ w1,
                      const float* __restrict__ w2, const float* __restrict__ w3,
                      const float* __restrict__ opw, const float* __restrict__ wf,
                      const float* __restrict__ ipw,
                      float* __restrict__ wt, float* __restrict__ w2t,
                      float* __restrict__ wi)
{
    if (blockIdx.x < 144){
        int idx = blockIdx.x*256 + threadIdx.x;      // 0..36863
        int r = idx / 12288, rem = idx % 12288;
        int k = rem >> 6, o = rem & 63;
        const float* W = (r==0)?w1:(r==1)?w2:w3;
        wt[idx] = W[o*192 + k];
    } else if (blockIdx.x < 240){
        int idx = (blockIdx.x-144)*256 + threadIdx.x; // 0..24575
        int o = idx & 63, ri = idx >> 6;
        int r = ri >> 7, i = ri & 127;
        float acc = 0.f;
        for (int c2=0;c2<64;c2++)
            acc += opw[c2*128+i] * wf[o*192 + r*64 + c2];
        w2t[idx] = acc;
    } else {
        int idx = (blockIdx.x-240)*256 + threadIdx.x; // 0..16383
        int col = idx & 255, q = idx >> 8;
        wi[q*256 + col] = ipw[col*64 + q];
    }
}

// ======= K1: axis conv — 4o x 4w register tile, 2 rows/block, ic-quarters ==
__global__ __launch_bounds__(192) void k_conv(const float* __restrict__ x,
                       const float* __restrict__ wt,
                       const float* __restrict__ b1, const float* __restrict__ b2,
                       const float* __restrict__ b3,
                       float* __restrict__ u, float* __restrict__ ws)
{
    __shared__ __align__(16) float xs[2*1152];  // [rw][(ic2*3+t)*24 + w], 16 ic/phase
    __shared__ __align__(16) float wl[48*64];   // [k2*64 + o], 48 k/phase
    __shared__ float ssum[64], ssq[64];
    const int r = blockIdx.y;
    const int row0 = blockIdx.x*2;
    const float* Bz = (r==0)?b1:(r==1)?b2:b3;
    const int tid = threadIdx.x;

    if (tid < 64){ ssum[tid]=0.f; ssq[tid]=0.f; }

    const int rw = (tid >= 96) ? 1 : 0, t2 = tid - rw*96;
    const int og = t2 & 15, wg2 = t2 >> 4;
    const int o0 = og*4, w0 = wg2*4;
    float acc[4][4];
    {
        float b0 = Bz[o0], b1v = Bz[o0+1], b2v = Bz[o0+2], b3v = Bz[o0+3];
        #pragma unroll
        for (int wj=0;wj<4;wj++){ acc[0][wj]=b0; acc[1][wj]=b1v; acc[2][wj]=b2v; acc[3][wj]=b3v; }
    }

    const float* wtr = wt + (size_t)r*12288;
    const float* xrow = &xs[rw*1152];
    const int d0 = (row0)/24,   h0 = (row0)%24;
    const int d1 = (row0+1)/24, h1 = (row0+1)%24;

    for (int ph=0; ph<4; ph++){
        __syncthreads();
        for (int s = tid; s < 3072; s += 192)
            wl[s] = wtr[ph*3072 + s];
        for (int rw2=0; rw2<2; rw2++){
            int row = row0 + rw2;
            int d = rw2 ? d1 : d0, h = rw2 ? h1 : h0;
            for (int s = tid; s < 1152; s += 192){
                int w = s % 24; int kt = s / 24; int ic2 = kt/3, t = kt%3;
                int ic = ph*16 + ic2;
                int src = 0; bool valid = true;
                if (r==0){ int dd = d+t-1; valid = (dd>=0 && dd<24); src = (dd*24+h)*24 + w; }
                else if (r==1){ int hh = h+t-1; valid = (hh>=0 && hh<24); src = (d*24+hh)*24 + w; }
                else { int ww = w+t-1; valid = (ww>=0 && ww<24); src = row*24 + ww; }
                xs[rw2*1152 + s] = valid ? x[(size_t)ic*LTOT + src] : 0.f;
            }
        }
        __syncthreads();
        for (int ic2=0; ic2<16; ic2++){
            #pragma unroll
            for (int t=0;t<3;t++){
                float4 wv = *(const float4*)&wl[(ic2*3+t)*64 + o0];
                float4 xv = *(const float4*)&xrow[(ic2*3+t)*24 + w0];
                acc[0][0]=fmaf(wv.x,xv.x,acc[0][0]); acc[0][1]=fmaf(wv.x,xv.y,acc[0][1]);
                acc[0][2]=fmaf(wv.x,xv.z,acc[0][2]); acc[0][3]=fmaf(wv.x,xv.w,acc[0][3]);
                acc[1][0]=fmaf(wv.y,xv.x,acc[1][0]); acc[1][1]=fmaf(wv.y,xv.y,acc[1][1]);
                acc[1][2]=fmaf(wv.y,xv.z,acc[1][2]); acc[1][3]=fmaf(wv.y,xv.w,acc[1][3]);
                acc[2][0]=fmaf(wv.z,xv.x,acc[2][0]); acc[2][1]=fmaf(wv.z,xv.y,acc[2][1]);
                acc[2][2]=fmaf(wv.z,xv.z,acc[2][2]); acc[2][3]=fmaf(wv.z,xv.w,acc[2][3]);
                acc[3][0]=fmaf(wv.w,xv.x,acc[3][0]); acc[3][1]=fmaf(wv.w,xv.y,acc[3][1]);
                acc[3][2]=fmaf(wv.w,xv.z,acc[3][2]); acc[3][3]=fmaf(wv.w,xv.w,acc[3][3]);
            }
        }
    }

    size_t ub = ((size_t)r*LTOT + (size_t)(row0+rw)*24)*64;
    float ps[4]={0,0,0,0}, pq[4]={0,0,0,0};
    #pragma unroll
    for (int wj=0; wj<4; wj++){
        float4 v = make_float4(acc[0][wj],acc[1][wj],acc[2][wj],acc[3][wj]);
        *(float4*)&u[ub + (size_t)(w0+wj)*64 + o0] = v;
        ps[0]+=v.x; pq[0]+=v.x*v.x; ps[1]+=v.y; pq[1]+=v.y*v.y;
        ps[2]+=v.z; pq[2]+=v.z*v.z; ps[3]+=v.w; pq[3]+=v.w*v.w;
    }
    #pragma unroll
    for (int oj=0;oj<4;oj++){
        atomicAdd(&ssum[o0+oj], ps[oj]);
        atomicAdd(&ssq[o0+oj], pq[oj]);
    }
    __syncthreads();
    if (tid < 64){
        atomicAdd(&ws[r*64 + tid], ssum[tid]);
        atomicAdd(&ws[192 + r*64 + tid], ssq[tid]);
    }
}

// ================= K2: finalize branch IN stats ============================
__global__ __launch_bounds__(192) void k_stats1(float* ws){
    int t = threadIdx.x;   // 0..191
    float s = ws[t], q = ws[192+t];
    float m = s*(1.f/(float)LTOT);
    float v = q*(1.f/(float)LTOT) - m*m;
    ws[512+t] = m; ws[704+t] = rsqrtf(v + EPSF);
}

// == K4: fused IN+ReLU+LN + in_proj (lane=pos, scalar weights) + silu =======
__global__ __launch_bounds__(256, 4) void k_inproj(const float* __restrict__ u, float* __restrict__ xiT,
                         float* __restrict__ szT, const float* __restrict__ wi,
                         const float* __restrict__ cw, const float* __restrict__ cb,
                         const float* __restrict__ ws,
                         const float* g1,const float* be1,const float* g2,const float* be2,
                         const float* g3,const float* be3,
                         const float* lnw,const float* lnb)
{
    __shared__ float xl[64*65];                 // [c][p] padded, 16.6 KB
    const int tid = threadIdx.x, r = blockIdx.y;
    const int lane = tid & 63;
    const int wv = __builtin_amdgcn_readfirstlane(tid >> 6);
    const int l0 = blockIdx.x*64;
    size_t gbase = (size_t)r*LTOT + l0;

    {
        const float* g  = (r==0)?g1:(r==1)?g2:g3;
        const float* be = (r==0)?be1:(r==1)?be2:be3;
        float m  = ws[512 + r*64 + lane], rs = ws[704 + r*64 + lane];
        float gg = g[lane], bb = be[lane];
        float lw = lnw[lane], lb = lnb[lane];
        for (int j=0;j<16;j++){
            int p = wv*16 + j;
            float vv = u[(gbase+p)*64 + lane];
            vv = fmaxf((vv-m)*rs*gg + bb, 0.f);
            float s1 = sum16(vv), s2 = sum16(vv*vv);
            s1 += __shfl_xor(s1,16); s2 += __shfl_xor(s2,16);
            s1 += __shfl_xor(s1,32); s2 += __shfl_xor(s2,32);
            float mean = s1*(1.f/64.f);
            float var  = s2*(1.f/64.f) - mean*mean;
            xl[lane*65 + p] = (vv-mean)*rsqrtf(var+EPSF)*lw + lb;
        }
    }
    __syncthreads();

    float acc[64];
    #pragma unroll
    for (int j=0;j<64;j++) acc[j] = 0.f;
    const float* wbase = wi + wv*64;
    for (int q=0;q<64;q++){
        float xq = xl[q*65 + lane];
        const float* wq = wbase + q*256;
        #pragma unroll
        for (int j=0;j<64;j++)
            acc[j] = fmaf(wq[j], xq, acc[j]);
    }

    const bool isx = (wv < 2);
    float* dst = isx ? xiT : szT;
    const int c0 = (wv & 1)*64;
    #pragma unroll
    for (int j=0;j<64;j++){
        int c2 = c0 + j;
        float v;
        if (isx) v = siluf(fmaf(acc[j], cw[c2], cb[c2]));
        else     v = siluf(acc[j]);
        dst[((size_t)r*128 + c2)*LTOT + l0 + lane] = v;
    }
}

// ================= K5: x_proj + dt softplus -> transposed rows =============
__global__ __launch_bounds__(256) void k_xproj(const float* __restrict__ xiT, float* __restrict__ dtT,
                        float* __restrict__ BmT, float* __restrict__ CmT,
                        const float* __restrict__ xpw, const float* __restrict__ dtw,
                        const float* __restrict__ dtb)
{
    __shared__ __align__(16) float xt[128*36];   // [c*36 + p]
    __shared__ float ww[36*129];                 // [k*129 + c]
    __shared__ float sd[4*36];                   // dt-rank rows [k*36 + p]
    const int tid = threadIdx.x, r = blockIdx.y;
    const int l0 = blockIdx.x*32;

    for (int s = tid; s < 4096; s += 256){
        int c = s>>5, p = s&31;
        xt[c*36+p] = xiT[((size_t)r*128 + c)*LTOT + l0 + p];
    }
    for (int s = tid; s < 4608; s += 256){
        int k = s>>7, c = s&127;
        ww[k*129+c] = xpw[s];
    }
    __syncthreads();

    const int wv = tid>>6, lane = tid&63;
    float acc[8] = {0,0,0,0,0,0,0,0};
    if (lane < 36){
        const float* wrow = &ww[lane*129];
        for (int c=0;c<128;c++){
            float w = wrow[c];
            float4 a = *(const float4*)&xt[c*36 + wv*8];
            float4 b = *(const float4*)&xt[c*36 + wv*8 + 4];
            acc[0]=fmaf(w,a.x,acc[0]); acc[1]=fmaf(w,a.y,acc[1]);
            acc[2]=fmaf(w,a.z,acc[2]); acc[3]=fmaf(w,a.w,acc[3]);
            acc[4]=fmaf(w,b.x,acc[4]); acc[5]=fmaf(w,b.y,acc[5]);
            acc[6]=fmaf(w,b.z,acc[6]); acc[7]=fmaf(w,b.w,acc[7]);
        }
    }
    if (lane>=4 && lane<36){
        float* dst = (lane<20) ? BmT : CmT;
        int n = (lane<20) ? (lane-4) : (lane-20);
        size_t base = ((size_t)r*16 + n)*LTOT + l0 + wv*8;
        *(float4*)&dst[base]   = make_float4(acc[0],acc[1],acc[2],acc[3]);
        *(float4*)&dst[base+4] = make_float4(acc[4],acc[5],acc[6],acc[7]);
    }
    if (lane < 4){
        #pragma unroll
        for (int p=0;p<8;p++) sd[lane*36 + wv*8 + p] = acc[p];
    }
    __syncthreads();

    const int i = tid>>1, ph = tid&1;
    float4 dw = *(const float4*)&dtw[i*4];
    float db = dtb[i];
    float buf[16];
    #pragma unroll
    for (int t=0;t<16;t++){
        int p = ph*16 + t;
        float v = db + dw.x*sd[0*36+p] + dw.y*sd[1*36+p]
                     + dw.z*sd[2*36+p] + dw.w*sd[3*36+p];
        buf[t] = softplusf(v);
    }
    size_t base = ((size_t)r*128 + i)*LTOT + l0 + ph*16;
    #pragma unroll
    for (int q=0;q<4;q++){
        *(float4*)&dtT[base + 4*q] =
            make_float4(buf[4*q], buf[4*q+1], buf[4*q+2], buf[4*q+3]);
    }
}

// ====== K6: scan pass 1 — two-phase LDS staging (13 KB), chunk aggregates ==
__global__ __launch_bounds__(256) void k_scan1(const float* __restrict__ dtT, const float* __restrict__ BmT,
                        const float* __restrict__ xiT, const float* __restrict__ Alog,
                        float* __restrict__ aga, float* __restrict__ agb)
{
    __shared__ float4 sdt[16*17], sxi[16*17], sbm[16*17];   // 13 KB
    const int tid = threadIdx.x;
    const int n = tid & 15, il = tid >> 4;
    const int c = blockIdx.x, ib = blockIdx.y, r = blockIdx.z;
    const int i = ib*16 + il;

    const float A2 = -expf(Alog[i*16+n]) * 1.44269504f;
    float b = 0.f, sdtacc = 0.f;
    #define S1_STEP(dv,xv,bv) { float e=exp2f(A2*(dv)); b=fmaf(e,b,(dv)*(xv)*(bv)); }

    for (int ph2 = 0; ph2 < 2; ph2++){
        __syncthreads();
        {
            int ii = tid >> 4, t4 = tid & 15;
            size_t rowI = ((size_t)r*128 + ib*16 + ii)*LTOT + (size_t)c*CHL + (ph2*16 + t4)*4;
            size_t rowN = ((size_t)r*16  + ii)*LTOT + (size_t)c*CHL + (ph2*16 + t4)*4;
            sdt[ii*17 + t4] = *(const float4*)&dtT[rowI];
            sxi[ii*17 + t4] = *(const float4*)&xiT[rowI];
            sbm[ii*17 + t4] = *(const float4*)&BmT[rowN];
        }
        __syncthreads();
        for (int t4 = 0; t4 < 16; t4++){
            float4 d = sdt[il*17 + t4];
            float4 x = sxi[il*17 + t4];
            float4 m = sbm[n*17 + t4];
            sdtacc += ((d.x+d.y)+(d.z+d.w));
            S1_STEP(d.x,x.x,m.x) S1_STEP(d.y,x.y,m.y)
            S1_STEP(d.z,x.z,m.z) S1_STEP(d.w,x.w,m.w)
        }
    }
    size_t o = ((size_t)(r*NCH+c)*128 + i)*16 + n;
    aga[o] = exp2f(A2*sdtacc);
    agb[o] = b;
}

// ================= K7: scan pass 2 — combine chunk aggregates ==============
__global__ __launch_bounds__(512) void k_scan2(const float* __restrict__ aga, const float* __restrict__ agb,
                        float* __restrict__ seed)
{
    int t = blockIdx.x*512 + threadIdx.x;  // 0..6143
    int r = t >> 11, rem = t & 2047;
    float h = 0.f;
    for (int c=0;c<NCH;c++){
        size_t idx = (size_t)(r*NCH+c)*2048 + rem;
        float a = aga[idx], b = agb[idx];
        seed[idx] = h;
        h = fmaf(a, h, b);
    }
}

// == K8: scan pass 3 — two-phase LDS staging (17.4 KB); y_raw in sdt ========
__global__ __launch_bounds__(256) void k_scan3(const float* __restrict__ dtT, const float* __restrict__ BmT,
                        const float* __restrict__ CmT, const float* __restrict__ xiT,
                        float* __restrict__ szT, const float* __restrict__ Alog,
                        const float* __restrict__ Dp, const float* __restrict__ seed)
{
    __shared__ float4 sdt[16*17], sxi[16*17], sbm[16*17], scm[16*17]; // 17.4 KB
    const int tid = threadIdx.x;
    const int n = tid & 15, il = tid >> 4;
    const int c = blockIdx.x, ib = blockIdx.y, r = blockIdx.z;
    const int i = ib*16 + il;

    const float A2 = -expf(Alog[i*16+n]) * 1.44269504f;
    const float Dv = Dp[i];
    float h = seed[(size_t)(r*NCH+c)*2048 + (i*16+n)];

    #define S3_STEP(dv,xv,bv,cv,oyv) { \
        float e=exp2f(A2*(dv)); h=fmaf(e,h,(dv)*(xv)*(bv)); \
        float py=sum16(h*(cv)); oyv = fmaf((xv),Dv,py); }

    const int ii = tid >> 4, t4s = tid & 15;
    for (int ph2 = 0; ph2 < 2; ph2++){
        __syncthreads();
        {
            size_t rowI = ((size_t)r*128 + ib*16 + ii)*LTOT + (size_t)c*CHL + (ph2*16 + t4s)*4;
            size_t rowN = ((size_t)r*16  + ii)*LTOT + (size_t)c*CHL + (ph2*16 + t4s)*4;
            sdt[ii*17 + t4s] = *(const float4*)&dtT[rowI];
            sxi[ii*17 + t4s] = *(const float4*)&xiT[rowI];
            sbm[ii*17 + t4s] = *(const float4*)&BmT[rowN];
            scm[ii*17 + t4s] = *(const float4*)&CmT[rowN];
        }
        __syncthreads();
        for (int t4 = 0; t4 < 16; t4++){
            float4 d = sdt[il*17 + t4];
            float4 x = sxi[il*17 + t4];
            float4 m = sbm[n*17 + t4];
            float4 cv = scm[n*17 + t4];
            float4 yv;
            S3_STEP(d.x,x.x,m.x,cv.x, yv.x)
            S3_STEP(d.y,x.y,m.y,cv.y, yv.y)
            S3_STEP(d.z,x.z,m.z,cv.z, yv.z)
            S3_STEP(d.w,x.w,m.w,cv.w, yv.w)
            if (n==0) sdt[il*17 + t4] = yv;   // overwrite consumed slot with y_raw
        }
        __syncthreads();
        {
            size_t rowI = ((size_t)r*128 + ib*16 + ii)*LTOT + (size_t)c*CHL + (ph2*16 + t4s)*4;
            float4 yv = sdt[ii*17 + t4s];
            float4 s  = *(const float4*)&szT[rowI];
            *(float4*)&szT[rowI] = make_float4(yv.x*s.x, yv.y*s.y, yv.z*s.z, yv.w*s.w);
        }
    }
}

// ========== K10: out_proj∘conv GEMM — w fully unrolled into VGPRs ==========
__global__ __launch_bounds__(256, 1) void k_fin(const float* __restrict__ yT, const float* __restrict__ w2t,
                      const float* __restrict__ bfb, float* __restrict__ fin,
                      float* __restrict__ ws)
{
    __shared__ __align__(16) float yl[384*20];  // [k*20 + p], 30.7 KB
    __shared__ float part[4*16*64];             // [sg][p][o], 16 KB
    __shared__ float ssum[64], ssq[64];
    const int tid = threadIdx.x;
    const int l0 = blockIdx.x*16;
    const int o = tid & 63, sg = tid >> 6;

    for (int f = tid; f < 6144; f += 256){
        int k = f >> 4, p = f & 15;
        yl[k*20 + p] = yT[(size_t)k*LTOT + l0 + p];
    }
    float wreg[96];
    {
        const float* wp = w2t + (size_t)(sg*96)*64 + o;
        #pragma unroll
        for (int j=0;j<96;j++) wreg[j] = wp[(size_t)j*64];
    }
    if (tid < 64){ ssum[tid]=0.f; ssq[tid]=0.f; }
    __syncthreads();

    float acc[16];
    #pragma unroll
    for (int p=0;p<16;p++) acc[p]=0.f;
    const float* ylbase = &yl[sg*96*20];
    #pragma unroll
    for (int j=0;j<96;j++){
        float w = wreg[j];
        const float4* yp4 = (const float4*)&ylbase[j*20];
        float4 a = yp4[0], b = yp4[1], c = yp4[2], d = yp4[3];
        acc[0] =fmaf(w,a.x,acc[0]);  acc[1] =fmaf(w,a.y,acc[1]);
        acc[2] =fmaf(w,a.z,acc[2]);  acc[3] =fmaf(w,a.w,acc[3]);
        acc[4] =fmaf(w,b.x,acc[4]);  acc[5] =fmaf(w,b.y,acc[5]);
        acc[6] =fmaf(w,b.z,acc[6]);  acc[7] =fmaf(w,b.w,acc[7]);
        acc[8] =fmaf(w,c.x,acc[8]);  acc[9] =fmaf(w,c.y,acc[9]);
        acc[10]=fmaf(w,c.z,acc[10]); acc[11]=fmaf(w,c.w,acc[11]);
        acc[12]=fmaf(w,d.x,acc[12]); acc[13]=fmaf(w,d.y,acc[13]);
        acc[14]=fmaf(w,d.z,acc[14]); acc[15]=fmaf(w,d.w,acc[15]);
    }
    #pragma unroll
    for (int p=0;p<16;p++) part[(sg*16+p)*64 + o] = acc[p];
    __syncthreads();

    float bias = bfb[o];
    float ps=0.f, pq=0.f;
    #pragma unroll
    for (int j=0;j<4;j++){
        int p = sg + j*4;
        float s = part[(0*16+p)*64+o] + part[(1*16+p)*64+o]
                + part[(2*16+p)*64+o] + part[(3*16+p)*64+o] + bias;
        fin[(size_t)(l0+p)*64 + o] = s;
        ps += s; pq += s*s;
    }
    atomicAdd(&ssum[o], ps); atomicAdd(&ssq[o], pq);
    __syncthreads();
    if (tid<64){
        atomicAdd(&ws[384+tid], ssum[tid]);
        atomicAdd(&ws[448+tid], ssq[tid]);
    }
}

// ================= K11: finalize final IN stats ============================
__global__ __launch_bounds__(64) void k_statsF(float* ws){
    int t = threadIdx.x;  // 0..63
    float s = ws[384+t], q = ws[448+t];
    float m = s*(1.f/(float)LTOT);
    float v = q*(1.f/(float)LTOT) - m*m;
    ws[896+t] = m; ws[960+t] = rsqrtf(v + EPSF);
}

// ================= K12: final IN + ReLU + transpose + fp32 store ===========
__global__ __launch_bounds__(256) void k_out(const float* __restrict__ fin, const float* __restrict__ ws,
                      const float* __restrict__ gf, const float* __restrict__ bef,
                      float* __restrict__ out)
{
    __shared__ float tl[64*65];
    const int tid = threadIdx.x;
    const int l0 = blockIdx.x*64;
    for (int s=tid; s<4096; s+=256){
        int li = s>>6, o = s&63;
        float v = fin[(size_t)(l0+li)*64 + o];
        v = fmaxf((v - ws[896+o])*ws[960+o]*gf[o] + bef[o], 0.f);
        tl[o*65+li] = v;
    }
    __syncthreads();
    for (int s=tid; s<4096; s+=256){
        int o = s>>6, li = s&63;
        out[(size_t)o*LTOT + l0 + li] = tl[o*65+li];
    }
}

extern "C" void kernel_launch(void* const* d_in, const int* in_sizes, int n_in,
                              void* d_out, int out_size, void* d_ws, size_t ws_size,
                              hipStream_t stream)
{
    const float* X    = (const float*)d_in[0];
    const float* W1   = (const float*)d_in[1];  const float* B1  = (const float*)d_in[2];
    const float* G1   = (const float*)d_in[3];  const float* BE1 = (const float*)d_in[4];
    const float* W2   = (const float*)d_in[5];  const float* B2  = (const float*)d_in[6];
    const float* G2   = (const float*)d_in[7];  const float* BE2 = (const float*)d_in[8];
    const float* W3   = (const float*)d_in[9];  const float* B3  = (const float*)d_in[10];
    const float* G3   = (const float*)d_in[11]; const float* BE3 = (const float*)d_in[12];
    const float* LNW  = (const float*)d_in[13]; const float* LNB = (const float*)d_in[14];
    const float* IPW  = (const float*)d_in[15];
    const float* CW   = (const float*)d_in[16]; const float* CB  = (const float*)d_in[17];
    const float* XPW  = (const float*)d_in[18];
    const float* DTW  = (const float*)d_in[19]; const float* DTB = (const float*)d_in[20];
    const float* ALOG = (const float*)d_in[21]; const float* DP  = (const float*)d_in[22];
    const float* OPW  = (const float*)d_in[23];
    const float* WF   = (const float*)d_in[24]; const float* BF  = (const float*)d_in[25];
    const float* GF   = (const float*)d_in[26]; const float* BEF = (const float*)d_in[27];
    float* ws = (float*)d_ws;

    (void)hipMemsetAsync(d_ws, 0, 2048, stream);

    k_prep  <<<304, 256, 0, stream>>>(W1, W2, W3, OPW, WF, IPW,
                                      ws+OFF_WT, ws+OFF_W2, ws+OFF_WI);
    k_conv  <<<dim3(288,3), 192, 0, stream>>>(X, ws+OFF_WT, B1, B2, B3, ws+OFF_U, ws);
    k_stats1<<<1, 192, 0, stream>>>(ws);
    k_inproj<<<dim3(216,3), 256, 0, stream>>>(ws+OFF_U, ws+OFF_XIT, ws+OFF_SZT,
                                              ws+OFF_WI, CW, CB, ws,
                                              G1,BE1,G2,BE2,G3,BE3, LNW,LNB);
    k_xproj <<<dim3(432,3), 256, 0, stream>>>(ws+OFF_XIT, ws+OFF_DTT, ws+OFF_BMT,
                                              ws+OFF_CMT, XPW, DTW, DTB);
    k_scan1 <<<dim3(NCH,8,3), 256, 0, stream>>>(ws+OFF_DTT, ws+OFF_BMT, ws+OFF_XIT,
                                                ALOG, ws+OFF_AGA, ws+OFF_AGB);
    k_scan2 <<<12, 512, 0, stream>>>(ws+OFF_AGA, ws+OFF_AGB, ws+OFF_SEED);
    k_scan3 <<<dim3(NCH,8,3), 256, 0, stream>>>(ws+OFF_DTT, ws+OFF_BMT, ws+OFF_CMT,
                                                ws+OFF_XIT, ws+OFF_SZT, ALOG, DP,
                                                ws+OFF_SEED);
    k_fin   <<<864, 256, 0, stream>>>(ws+OFF_SZT, ws+OFF_W2, BF, ws+OFF_FIN, ws);
    k_statsF<<<1, 64, 0, stream>>>(ws);
    k_out   <<<216, 256, 0, stream>>>(ws+OFF_FIN, ws, GF, BEF, (float*)d_out);
}

// Round 21
// 372.357 us; speedup vs baseline: 1.1953x; 1.1953x over previous
//
#include <hip/hip_runtime.h>

#define LTOT 13824          // 24*24*24
#define NCH 108             // scan chunks (fine)
#define CHL 128             // chunk length (108*128 = 13824)
#define EPSF 1e-5f

// ---------- workspace layout (floats) ----------
static const size_t OFF_U   = 1024;                 // conv out; DEAD after inproj
static const size_t NU      = (size_t)3*LTOT*64;    // 2654208
static const size_t NXI     = (size_t)3*LTOT*128;   // 5308416
static const size_t NBM     = (size_t)3*LTOT*16;    // 663552
static const size_t NAG     = (size_t)3*NCH*128*16; // 663552
static const size_t OFF_XIT = OFF_U   + NU;         // xiT[(r*128+i)][l]
static const size_t OFF_SZT = OFF_XIT + NXI;        // szT -> becomes yT in-place
static const size_t OFF_DTT = OFF_SZT + NXI;        // dtT[(r*128+i)][l]
static const size_t OFF_BMT = OFF_DTT + NXI;        // BmT[(r*16+n)][l]
static const size_t OFF_CMT = OFF_BMT + NBM;
static const size_t OFF_W2  = OFF_CMT + NBM;        // 384*64
static const size_t OFF_WT  = OFF_W2 + 24576;       // 3*192*64 transposed conv weights
static const size_t OFF_WI  = OFF_WT + 36864;       // in_proj weights transposed [q][col] 64*256
// scan scratch overlaid on dead U region
static const size_t OFF_AGA = OFF_U;
static const size_t OFF_AGB = OFF_U + NAG;
static const size_t OFF_SEED= OFF_U + 2*NAG;
static const size_t OFF_FIN = OFF_DTT;              // dtT dead after scan3

__device__ __forceinline__ float sigm(float x){ return 1.f/(1.f+__expf(-x)); }
__device__ __forceinline__ float siluf(float x){ return x*sigm(x); }
__device__ __forceinline__ float softplusf(float x){
    return fmaxf(x,0.f) + log1pf(__expf(-fabsf(x)));
}

// all-VALU cross-lane adds via DPP (no LDS pipe)
template<int CTRL>
__device__ __forceinline__ float dpp_add(float x){
    int v = __builtin_amdgcn_update_dpp(0, __float_as_int(x), CTRL, 0xf, 0xf, true);
    return x + __int_as_float(v);
}
__device__ __forceinline__ float sum16(float x){   // sum within each 16-lane row
    x = dpp_add<0xB1>(x);    // quad_perm xor1
    x = dpp_add<0x4E>(x);    // quad_perm xor2
    x = dpp_add<0x141>(x);   // row_half_mirror
    x = dpp_add<0x140>(x);   // row_mirror
    return x;
}

// ===== K0: weight prep — conv transpose, out_proj∘conv fusion, in_proj^T ===
__global__ __launch_bounds__(256) void k_prep(const float* __restrict__ w1,
                      const float* __restrict__ w2, const float* __restrict__ w3,
                      const float* __restrict__ opw, const float* __restrict__ wf,
                      const float* __restrict__ ipw,
                      float* __restrict__ wt, float* __restrict__ w2t,
                      float* __restrict__ wi)
{
    if (blockIdx.x < 144){
        int idx = blockIdx.x*256 + threadIdx.x;      // 0..36863
        int r = idx / 12288, rem = idx % 12288;
        int k = rem >> 6, o = rem & 63;
        const float* W = (r==0)?w1:(r==1)?w2:w3;
        wt[idx] = W[o*192 + k];
    } else if (blockIdx.x < 240){
        int idx = (blockIdx.x-144)*256 + threadIdx.x; // 0..24575
        int o = idx & 63, ri = idx >> 6;
        int r = ri >> 7, i = ri & 127;
        float acc = 0.f;
        for (int c2=0;c2<64;c2++)
            acc += opw[c2*128+i] * wf[o*192 + r*64 + c2];
        w2t[idx] = acc;
    } else {
        int idx = (blockIdx.x-240)*256 + threadIdx.x; // 0..16383
        int col = idx & 255, q = idx >> 8;
        wi[q*256 + col] = ipw[col*64 + q];
    }
}

// ======= K1: axis conv — 4o x 4w register tile, 2 rows/block, ic-quarters ==
__global__ __launch_bounds__(192) void k_conv(const float* __restrict__ x,
                       const float* __restrict__ wt,
                       const float* __restrict__ b1, const float* __restrict__ b2,
                       const float* __restrict__ b3,
                       float* __restrict__ u, float* __restrict__ ws)
{
    __shared__ __align__(16) float xs[2*1152];  // [rw][(ic2*3+t)*24 + w], 16 ic/phase
    __shared__ __align__(16) float wl[48*64];   // [k2*64 + o], 48 k/phase
    __shared__ float ssum[64], ssq[64];
    const int r = blockIdx.y;
    const int row0 = blockIdx.x*2;
    const float* Bz = (r==0)?b1:(r==1)?b2:b3;
    const int tid = threadIdx.x;

    if (tid < 64){ ssum[tid]=0.f; ssq[tid]=0.f; }

    const int rw = (tid >= 96) ? 1 : 0, t2 = tid - rw*96;
    const int og = t2 & 15, wg2 = t2 >> 4;
    const int o0 = og*4, w0 = wg2*4;
    float acc[4][4];
    {
        float b0 = Bz[o0], b1v = Bz[o0+1], b2v = Bz[o0+2], b3v = Bz[o0+3];
        #pragma unroll
        for (int wj=0;wj<4;wj++){ acc[0][wj]=b0; acc[1][wj]=b1v; acc[2][wj]=b2v; acc[3][wj]=b3v; }
    }

    const float* wtr = wt + (size_t)r*12288;
    const float* xrow = &xs[rw*1152];
    const int d0 = (row0)/24,   h0 = (row0)%24;
    const int d1 = (row0+1)/24, h1 = (row0+1)%24;

    for (int ph=0; ph<4; ph++){
        __syncthreads();
        for (int s = tid; s < 3072; s += 192)
            wl[s] = wtr[ph*3072 + s];
        for (int rw2=0; rw2<2; rw2++){
            int row = row0 + rw2;
            int d = rw2 ? d1 : d0, h = rw2 ? h1 : h0;
            for (int s = tid; s < 1152; s += 192){
                int w = s % 24; int kt = s / 24; int ic2 = kt/3, t = kt%3;
                int ic = ph*16 + ic2;
                int src = 0; bool valid = true;
                if (r==0){ int dd = d+t-1; valid = (dd>=0 && dd<24); src = (dd*24+h)*24 + w; }
                else if (r==1){ int hh = h+t-1; valid = (hh>=0 && hh<24); src = (d*24+hh)*24 + w; }
                else { int ww = w+t-1; valid = (ww>=0 && ww<24); src = row*24 + ww; }
                xs[rw2*1152 + s] = valid ? x[(size_t)ic*LTOT + src] : 0.f;
            }
        }
        __syncthreads();
        for (int ic2=0; ic2<16; ic2++){
            #pragma unroll
            for (int t=0;t<3;t++){
                float4 wv = *(const float4*)&wl[(ic2*3+t)*64 + o0];
                float4 xv = *(const float4*)&xrow[(ic2*3+t)*24 + w0];
                acc[0][0]=fmaf(wv.x,xv.x,acc[0][0]); acc[0][1]=fmaf(wv.x,xv.y,acc[0][1]);
                acc[0][2]=fmaf(wv.x,xv.z,acc[0][2]); acc[0][3]=fmaf(wv.x,xv.w,acc[0][3]);
                acc[1][0]=fmaf(wv.y,xv.x,acc[1][0]); acc[1][1]=fmaf(wv.y,xv.y,acc[1][1]);
                acc[1][2]=fmaf(wv.y,xv.z,acc[1][2]); acc[1][3]=fmaf(wv.y,xv.w,acc[1][3]);
                acc[2][0]=fmaf(wv.z,xv.x,acc[2][0]); acc[2][1]=fmaf(wv.z,xv.y,acc[2][1]);
                acc[2][2]=fmaf(wv.z,xv.z,acc[2][2]); acc[2][3]=fmaf(wv.z,xv.w,acc[2][3]);
                acc[3][0]=fmaf(wv.w,xv.x,acc[3][0]); acc[3][1]=fmaf(wv.w,xv.y,acc[3][1]);
                acc[3][2]=fmaf(wv.w,xv.z,acc[3][2]); acc[3][3]=fmaf(wv.w,xv.w,acc[3][3]);
            }
        }
    }

    size_t ub = ((size_t)r*LTOT + (size_t)(row0+rw)*24)*64;
    float ps[4]={0,0,0,0}, pq[4]={0,0,0,0};
    #pragma unroll
    for (int wj=0; wj<4; wj++){
        float4 v = make_float4(acc[0][wj],acc[1][wj],acc[2][wj],acc[3][wj]);
        *(float4*)&u[ub + (size_t)(w0+wj)*64 + o0] = v;
        ps[0]+=v.x; pq[0]+=v.x*v.x; ps[1]+=v.y; pq[1]+=v.y*v.y;
        ps[2]+=v.z; pq[2]+=v.z*v.z; ps[3]+=v.w; pq[3]+=v.w*v.w;
    }
    #pragma unroll
    for (int oj=0;oj<4;oj++){
        atomicAdd(&ssum[o0+oj], ps[oj]);
        atomicAdd(&ssq[o0+oj], pq[oj]);
    }
    __syncthreads();
    if (tid < 64){
        atomicAdd(&ws[r*64 + tid], ssum[tid]);
        atomicAdd(&ws[192 + r*64 + tid], ssq[tid]);
    }
}

// ================= K2: finalize branch IN stats ============================
__global__ __launch_bounds__(192) void k_stats1(float* ws){
    int t = threadIdx.x;   // 0..191
    float s = ws[t], q = ws[192+t];
    float m = s*(1.f/(float)LTOT);
    float v = q*(1.f/(float)LTOT) - m*m;
    ws[512+t] = m; ws[704+t] = rsqrtf(v + EPSF);
}

// == K4: fused IN+ReLU+LN + in_proj (lane=pos, scalar weights) + silu =======
__global__ __launch_bounds__(256, 4) void k_inproj(const float* __restrict__ u, float* __restrict__ xiT,
                         float* __restrict__ szT, const float* __restrict__ wi,
                         const float* __restrict__ cw, const float* __restrict__ cb,
                         const float* __restrict__ ws,
                         const float* g1,const float* be1,const float* g2,const float* be2,
                         const float* g3,const float* be3,
                         const float* lnw,const float* lnb)
{
    __shared__ float xl[64*65];                 // [c][p] padded, 16.6 KB
    const int tid = threadIdx.x, r = blockIdx.y;
    const int lane = tid & 63;
    const int wv = __builtin_amdgcn_readfirstlane(tid >> 6);
    const int l0 = blockIdx.x*64;
    size_t gbase = (size_t)r*LTOT + l0;

    {
        const float* g  = (r==0)?g1:(r==1)?g2:g3;
        const float* be = (r==0)?be1:(r==1)?be2:be3;
        float m  = ws[512 + r*64 + lane], rs = ws[704 + r*64 + lane];
        float gg = g[lane], bb = be[lane];
        float lw = lnw[lane], lb = lnb[lane];
        for (int j=0;j<16;j++){
            int p = wv*16 + j;
            float vv = u[(gbase+p)*64 + lane];
            vv = fmaxf((vv-m)*rs*gg + bb, 0.f);
            float s1 = sum16(vv), s2 = sum16(vv*vv);
            s1 += __shfl_xor(s1,16); s2 += __shfl_xor(s2,16);
            s1 += __shfl_xor(s1,32); s2 += __shfl_xor(s2,32);
            float mean = s1*(1.f/64.f);
            float var  = s2*(1.f/64.f) - mean*mean;
            xl[lane*65 + p] = (vv-mean)*rsqrtf(var+EPSF)*lw + lb;
        }
    }
    __syncthreads();

    float acc[64];
    #pragma unroll
    for (int j=0;j<64;j++) acc[j] = 0.f;
    const float* wbase = wi + wv*64;
    for (int q=0;q<64;q++){
        float xq = xl[q*65 + lane];
        const float* wq = wbase + q*256;
        #pragma unroll
        for (int j=0;j<64;j++)
            acc[j] = fmaf(wq[j], xq, acc[j]);
    }

    const bool isx = (wv < 2);
    float* dst = isx ? xiT : szT;
    const int c0 = (wv & 1)*64;
    #pragma unroll
    for (int j=0;j<64;j++){
        int c2 = c0 + j;
        float v;
        if (isx) v = siluf(fmaf(acc[j], cw[c2], cb[c2]));
        else     v = siluf(acc[j]);
        dst[((size_t)r*128 + c2)*LTOT + l0 + lane] = v;
    }
}

// ================= K5: x_proj + dt softplus -> transposed rows =============
__global__ __launch_bounds__(256) void k_xproj(const float* __restrict__ xiT, float* __restrict__ dtT,
                        float* __restrict__ BmT, float* __restrict__ CmT,
                        const float* __restrict__ xpw, const float* __restrict__ dtw,
                        const float* __restrict__ dtb)
{
    __shared__ __align__(16) float xt[128*36];   // [c*36 + p]
    __shared__ float ww[36*129];                 // [k*129 + c]
    __shared__ float sd[4*36];                   // dt-rank rows [k*36 + p]
    const int tid = threadIdx.x, r = blockIdx.y;
    const int l0 = blockIdx.x*32;

    for (int s = tid; s < 4096; s += 256){
        int c = s>>5, p = s&31;
        xt[c*36+p] = xiT[((size_t)r*128 + c)*LTOT + l0 + p];
    }
    for (int s = tid; s < 4608; s += 256){
        int k = s>>7, c = s&127;
        ww[k*129+c] = xpw[s];
    }
    __syncthreads();

    const int wv = tid>>6, lane = tid&63;
    float acc[8] = {0,0,0,0,0,0,0,0};
    if (lane < 36){
        const float* wrow = &ww[lane*129];
        for (int c=0;c<128;c++){
            float w = wrow[c];
            float4 a = *(const float4*)&xt[c*36 + wv*8];
            float4 b = *(const float4*)&xt[c*36 + wv*8 + 4];
            acc[0]=fmaf(w,a.x,acc[0]); acc[1]=fmaf(w,a.y,acc[1]);
            acc[2]=fmaf(w,a.z,acc[2]); acc[3]=fmaf(w,a.w,acc[3]);
            acc[4]=fmaf(w,b.x,acc[4]); acc[5]=fmaf(w,b.y,acc[5]);
            acc[6]=fmaf(w,b.z,acc[6]); acc[7]=fmaf(w,b.w,acc[7]);
        }
    }
    if (lane>=4 && lane<36){
        float* dst = (lane<20) ? BmT : CmT;
        int n = (lane<20) ? (lane-4) : (lane-20);
        size_t base = ((size_t)r*16 + n)*LTOT + l0 + wv*8;
        *(float4*)&dst[base]   = make_float4(acc[0],acc[1],acc[2],acc[3]);
        *(float4*)&dst[base+4] = make_float4(acc[4],acc[5],acc[6],acc[7]);
    }
    if (lane < 4){
        #pragma unroll
        for (int p=0;p<8;p++) sd[lane*36 + wv*8 + p] = acc[p];
    }
    __syncthreads();

    const int i = tid>>1, ph = tid&1;
    float4 dw = *(const float4*)&dtw[i*4];
    float db = dtb[i];
    float buf[16];
    #pragma unroll
    for (int t=0;t<16;t++){
        int p = ph*16 + t;
        float v = db + dw.x*sd[0*36+p] + dw.y*sd[1*36+p]
                     + dw.z*sd[2*36+p] + dw.w*sd[3*36+p];
        buf[t] = softplusf(v);
    }
    size_t base = ((size_t)r*128 + i)*LTOT + l0 + ph*16;
    #pragma unroll
    for (int q=0;q<4;q++){
        *(float4*)&dtT[base + 4*q] =
            make_float4(buf[4*q], buf[4*q+1], buf[4*q+2], buf[4*q+3]);
    }
}

// ================= K6: scan pass 1 — LDS-staged chunk aggregates ===========
__global__ __launch_bounds__(256) void k_scan1(const float* __restrict__ dtT, const float* __restrict__ BmT,
                        const float* __restrict__ xiT, const float* __restrict__ Alog,
                        float* __restrict__ aga, float* __restrict__ agb)
{
    __shared__ float4 sdt[16*33], sxi[16*33], sbm[16*33];   // 25 KB
    const int tid = threadIdx.x;
    const int n = tid & 15, il = tid >> 4;
    const int c = blockIdx.x, ib = blockIdx.y, r = blockIdx.z;
    const int i = ib*16 + il;

    for (int f = tid; f < 512; f += 256){
        int ii = f >> 5, t4 = f & 31;
        size_t rowI = ((size_t)r*128 + ib*16 + ii)*LTOT + (size_t)c*CHL + t4*4;
        size_t rowN = ((size_t)r*16  + ii)*LTOT + (size_t)c*CHL + t4*4;
        sdt[ii*33 + t4] = *(const float4*)&dtT[rowI];
        sxi[ii*33 + t4] = *(const float4*)&xiT[rowI];
        sbm[ii*33 + t4] = *(const float4*)&BmT[rowN];
    }
    __syncthreads();

    const float A2 = -expf(Alog[i*16+n]) * 1.44269504f;
    float b = 0.f, sdtacc = 0.f;
    #define S1_STEP(dv,xv,bv) { float e=exp2f(A2*(dv)); b=fmaf(e,b,(dv)*(xv)*(bv)); }
    for (int t4 = 0; t4 < 32; t4++){
        float4 d = sdt[il*33 + t4];
        float4 x = sxi[il*33 + t4];
        float4 m = sbm[n*33 + t4];
        sdtacc += ((d.x+d.y)+(d.z+d.w));
        S1_STEP(d.x,x.x,m.x) S1_STEP(d.y,x.y,m.y)
        S1_STEP(d.z,x.z,m.z) S1_STEP(d.w,x.w,m.w)
    }
    size_t o = ((size_t)(r*NCH+c)*128 + i)*16 + n;
    aga[o] = exp2f(A2*sdtacc);
    agb[o] = b;
}

// ================= K7: scan pass 2 — combine chunk aggregates ==============
__global__ __launch_bounds__(512) void k_scan2(const float* __restrict__ aga, const float* __restrict__ agb,
                        float* __restrict__ seed)
{
    int t = blockIdx.x*512 + threadIdx.x;  // 0..6143
    int r = t >> 11, rem = t & 2047;
    float h = 0.f;
    for (int c=0;c<NCH;c++){
        size_t idx = (size_t)(r*NCH+c)*2048 + rem;
        float a = aga[idx], b = agb[idx];
        seed[idx] = h;
        h = fmaf(a, h, b);
    }
}

// ====== K8: scan pass 3 — LDS-staged replay; y_raw into sdt, sz at store ===
__global__ __launch_bounds__(256) void k_scan3(const float* __restrict__ dtT, const float* __restrict__ BmT,
                        const float* __restrict__ CmT, const float* __restrict__ xiT,
                        float* __restrict__ szT, const float* __restrict__ Alog,
                        const float* __restrict__ Dp, const float* __restrict__ seed)
{
    __shared__ float4 sdt[16*33], sxi[16*33], sbm[16*33], scm[16*33]; // 33 KB
    const int tid = threadIdx.x;
    const int n = tid & 15, il = tid >> 4;
    const int c = blockIdx.x, ib = blockIdx.y, r = blockIdx.z;
    const int i = ib*16 + il;

    for (int f = tid; f < 512; f += 256){
        int ii = f >> 5, t4 = f & 31;
        size_t rowI = ((size_t)r*128 + ib*16 + ii)*LTOT + (size_t)c*CHL + t4*4;
        size_t rowN = ((size_t)r*16  + ii)*LTOT + (size_t)c*CHL + t4*4;
        sdt[ii*33 + t4] = *(const float4*)&dtT[rowI];
        sxi[ii*33 + t4] = *(const float4*)&xiT[rowI];
        sbm[ii*33 + t4] = *(const float4*)&BmT[rowN];
        scm[ii*33 + t4] = *(const float4*)&CmT[rowN];
    }
    __syncthreads();

    const float A2 = -expf(Alog[i*16+n]) * 1.44269504f;
    const float Dv = Dp[i];
    float h = seed[(size_t)(r*NCH+c)*2048 + (i*16+n)];

    #define S3_STEP(dv,xv,bv,cv,oyv) { \
        float e=exp2f(A2*(dv)); h=fmaf(e,h,(dv)*(xv)*(bv)); \
        float py=sum16(h*(cv)); oyv = fmaf((xv),Dv,py); }
    for (int t4 = 0; t4 < 32; t4++){
        float4 d = sdt[il*33 + t4];
        float4 x = sxi[il*33 + t4];
        float4 m = sbm[n*33 + t4];
        float4 cv = scm[n*33 + t4];
        float4 yv;
        S3_STEP(d.x,x.x,m.x,cv.x, yv.x)
        S3_STEP(d.y,x.y,m.y,cv.y, yv.y)
        S3_STEP(d.z,x.z,m.z,cv.z, yv.z)
        S3_STEP(d.w,x.w,m.w,cv.w, yv.w)
        if (n==0) sdt[il*33 + t4] = yv;   // overwrite consumed slot with y_raw
    }
    __syncthreads();

    for (int f = tid; f < 512; f += 256){
        int ii = f >> 5, t4 = f & 31;
        size_t rowI = ((size_t)r*128 + ib*16 + ii)*LTOT + (size_t)c*CHL + t4*4;
        float4 yv = sdt[ii*33 + t4];
        float4 s  = *(const float4*)&szT[rowI];
        *(float4*)&szT[rowI] = make_float4(yv.x*s.x, yv.y*s.y, yv.z*s.z, yv.w*s.w);
    }
}

// ========== K10: out_proj∘conv GEMM — w fully unrolled into VGPRs ==========
__global__ __launch_bounds__(256, 1) void k_fin(const float* __restrict__ yT, const float* __restrict__ w2t,
                      const float* __restrict__ bfb, float* __restrict__ fin,
                      float* __restrict__ ws)
{
    __shared__ __align__(16) float yl[384*20];  // [k*20 + p], 30.7 KB
    __shared__ float part[4*16*64];             // [sg][p][o], 16 KB
    __shared__ float ssum[64], ssq[64];
    const int tid = threadIdx.x;
    const int l0 = blockIdx.x*16;
    const int o = tid & 63, sg = tid >> 6;

    for (int f = tid; f < 6144; f += 256){
        int k = f >> 4, p = f & 15;
        yl[k*20 + p] = yT[(size_t)k*LTOT + l0 + p];
    }
    float wreg[96];
    {
        const float* wp = w2t + (size_t)(sg*96)*64 + o;
        #pragma unroll
        for (int j=0;j<96;j++) wreg[j] = wp[(size_t)j*64];
    }
    if (tid < 64){ ssum[tid]=0.f; ssq[tid]=0.f; }
    __syncthreads();

    float acc[16];
    #pragma unroll
    for (int p=0;p<16;p++) acc[p]=0.f;
    const float* ylbase = &yl[sg*96*20];
    #pragma unroll
    for (int j=0;j<96;j++){
        float w = wreg[j];
        const float4* yp4 = (const float4*)&ylbase[j*20];
        float4 a = yp4[0], b = yp4[1], c = yp4[2], d = yp4[3];
        acc[0] =fmaf(w,a.x,acc[0]);  acc[1] =fmaf(w,a.y,acc[1]);
        acc[2] =fmaf(w,a.z,acc[2]);  acc[3] =fmaf(w,a.w,acc[3]);
        acc[4] =fmaf(w,b.x,acc[4]);  acc[5] =fmaf(w,b.y,acc[5]);
        acc[6] =fmaf(w,b.z,acc[6]);  acc[7] =fmaf(w,b.w,acc[7]);
        acc[8] =fmaf(w,c.x,acc[8]);  acc[9] =fmaf(w,c.y,acc[9]);
        acc[10]=fmaf(w,c.z,acc[10]); acc[11]=fmaf(w,c.w,acc[11]);
        acc[12]=fmaf(w,d.x,acc[12]); acc[13]=fmaf(w,d.y,acc[13]);
        acc[14]=fmaf(w,d.z,acc[14]); acc[15]=fmaf(w,d.w,acc[15]);
    }
    #pragma unroll
    for (int p=0;p<16;p++) part[(sg*16+p)*64 + o] = acc[p];
    __syncthreads();

    float bias = bfb[o];
    float ps=0.f, pq=0.f;
    #pragma unroll
    for (int j=0;j<4;j++){
        int p = sg + j*4;
        float s = part[(0*16+p)*64+o] + part[(1*16+p)*64+o]
                + part[(2*16+p)*64+o] + part[(3*16+p)*64+o] + bias;
        fin[(size_t)(l0+p)*64 + o] = s;
        ps += s; pq += s*s;
    }
    atomicAdd(&ssum[o], ps); atomicAdd(&ssq[o], pq);
    __syncthreads();
    if (tid<64){
        atomicAdd(&ws[384+tid], ssum[tid]);
        atomicAdd(&ws[448+tid], ssq[tid]);
    }
}

// ================= K11: finalize final IN stats ============================
__global__ __launch_bounds__(64) void k_statsF(float* ws){
    int t = threadIdx.x;  // 0..63
    float s = ws[384+t], q = ws[448+t];
    float m = s*(1.f/(float)LTOT);
    float v = q*(1.f/(float)LTOT) - m*m;
    ws[896+t] = m; ws[960+t] = rsqrtf(v + EPSF);
}

// ================= K12: final IN + ReLU + transpose + fp32 store ===========
__global__ __launch_bounds__(256) void k_out(const float* __restrict__ fin, const float* __restrict__ ws,
                      const float* __restrict__ gf, const float* __restrict__ bef,
                      float* __restrict__ out)
{
    __shared__ float tl[64*65];
    const int tid = threadIdx.x;
    const int l0 = blockIdx.x*64;
    for (int s=tid; s<4096; s+=256){
        int li = s>>6, o = s&63;
        float v = fin[(size_t)(l0+li)*64 + o];
        v = fmaxf((v - ws[896+o])*ws[960+o]*gf[o] + bef[o], 0.f);
        tl[o*65+li] = v;
    }
    __syncthreads();
    for (int s=tid; s<4096; s+=256){
        int o = s>>6, li = s&63;
        out[(size_t)o*LTOT + l0 + li] = tl[o*65+li];
    }
}

extern "C" void kernel_launch(void* const* d_in, const int* in_sizes, int n_in,
                              void* d_out, int out_size, void* d_ws, size_t ws_size,
                              hipStream_t stream)
{
    const float* X    = (const float*)d_in[0];
    const float* W1   = (const float*)d_in[1];  const float* B1  = (const float*)d_in[2];
    const float* G1   = (const float*)d_in[3];  const float* BE1 = (const float*)d_in[4];
    const float* W2   = (const float*)d_in[5];  const float* B2  = (const float*)d_in[6];
    const float* G2   = (const float*)d_in[7];  const float* BE2 = (const float*)d_in[8];
    const float* W3   = (const float*)d_in[9];  const float* B3  = (const float*)d_in[10];
    const float* G3   = (const float*)d_in[11]; const float* BE3 = (const float*)d_in[12];
    const float* LNW  = (const float*)d_in[13]; const float* LNB = (const float*)d_in[14];
    const float* IPW  = (const float*)d_in[15];
    const float* CW   = (const float*)d_in[16]; const float* CB  = (const float*)d_in[17];
    const float* XPW  = (const float*)d_in[18];
    const float* DTW  = (const float*)d_in[19]; const float* DTB = (const float*)d_in[20];
    const float* ALOG = (const float*)d_in[21]; const float* DP  = (const float*)d_in[22];
    const float* OPW  = (const float*)d_in[23];
    const float* WF   = (const float*)d_in[24]; const float* BF  = (const float*)d_in[25];
    const float* GF   = (const float*)d_in[26]; const float* BEF = (const float*)d_in[27];
    float* ws = (float*)d_ws;

    (void)hipMemsetAsync(d_ws, 0, 2048, stream);

    k_prep  <<<304, 256, 0, stream>>>(W1, W2, W3, OPW, WF, IPW,
                                      ws+OFF_WT, ws+OFF_W2, ws+OFF_WI);
    k_conv  <<<dim3(288,3), 192, 0, stream>>>(X, ws+OFF_WT, B1, B2, B3, ws+OFF_U, ws);
    k_stats1<<<1, 192, 0, stream>>>(ws);
    k_inproj<<<dim3(216,3), 256, 0, stream>>>(ws+OFF_U, ws+OFF_XIT, ws+OFF_SZT,
                                              ws+OFF_WI, CW, CB, ws,
                                              G1,BE1,G2,BE2,G3,BE3, LNW,LNB);
    k_xproj <<<dim3(432,3), 256, 0, stream>>>(ws+OFF_XIT, ws+OFF_DTT, ws+OFF_BMT,
                                              ws+OFF_CMT, XPW, DTW, DTB);
    k_scan1 <<<dim3(NCH,8,3), 256, 0, stream>>>(ws+OFF_DTT, ws+OFF_BMT, ws+OFF_XIT,
                                                ALOG, ws+OFF_AGA, ws+OFF_AGB);
    k_scan2 <<<12, 512, 0, stream>>>(ws+OFF_AGA, ws+OFF_AGB, ws+OFF_SEED);
    k_scan3 <<<dim3(NCH,8,3), 256, 0, stream>>>(ws+OFF_DTT, ws+OFF_BMT, ws+OFF_CMT,
                                                ws+OFF_XIT, ws+OFF_SZT, ALOG, DP,
                                                ws+OFF_SEED);
    k_fin   <<<864, 256, 0, stream>>>(ws+OFF_SZT, ws+OFF_W2, BF, ws+OFF_FIN, ws);
    k_statsF<<<1, 64, 0, stream>>>(ws);
    k_out   <<<216, 256, 0, stream>>>(ws+OFF_FIN, ws, GF, BEF, (float*)d_out);
}